// Round 4
// baseline (99.789 us; speedup 1.0000x reference)
//
#include <hip/hip_runtime.h>
#include <cstdint>
#include <cstddef>

// Problem constants (fixed by reference setup_inputs: N=10000, D=256, pos in [0,512)^2)
#define FD    256     // feature dim
#define KS    30      // spatial k
#define KF    6       // feature k
#define CSH   4       // cell size 16 px
#define GW    32      // 32x32 cell grid
#define NCELLS (GW*GW)
#define BCAP  40      // bucket capacity/cell (Poisson lambda=9.8; P(>40)~1e-13; overflow->ovf, still exact)
#define OVCAP 128     // global overflow list capacity
#define KREG  8       // candidate key slots per lane (wave covers 512; R=2 square ~245)
#define SCAPW 96      // survivors per wave (~40-60 typical; clamp guard beyond)
#define MAXC  100     // max cells per round (R<=4 square = 81)
#define NGRP  8       // dot phase: 8 groups x 4 candidates (30 real + 2 padded)

// Compiler memory fence at wave-synchronous LDS phase edges (HW LDS is in-order per wave).
#define WFENCE() __threadfence_block()

// ---- DPP cross-lane helpers: VALU-pipe replacements for ds_bpermute shuffles ----
// row_shr:N = lane i gets lane i-N (within 16-lane row); row_shl:N = lane i gets i+N.
// update_dpp(old=0,...) -> invalid/masked lanes contribute 0 to the add.
template <int CTRL, int RM, int BM>
__device__ __forceinline__ int dpp_add_i(int x) {
  return x + __builtin_amdgcn_update_dpp(0, x, CTRL, RM, BM, false);
}
// Canonical 64-lane inclusive scan: 4x row_shr + row_bcast15(rows 1,3) + row_bcast31(rows 2,3).
__device__ __forceinline__ int iscan64(int x) {
  x = dpp_add_i<0x111, 0xF, 0xF>(x);   // row_shr:1
  x = dpp_add_i<0x112, 0xF, 0xF>(x);   // row_shr:2
  x = dpp_add_i<0x114, 0xF, 0xF>(x);   // row_shr:4
  x = dpp_add_i<0x118, 0xF, 0xF>(x);   // row_shr:8
  x = dpp_add_i<0x142, 0xA, 0xF>(x);   // row_bcast:15 -> rows 1,3
  x = dpp_add_i<0x143, 0xC, 0xF>(x);   // row_bcast:31 -> rows 2,3
  return x;
}
// Butterfly step lane i += lane i+N (in-row, row_shl:N). Bit-identical to __shfl_down
// for every lane that feeds lane 0's reduction tree (steps <=8 only source in-row lanes).
template <int CTRL>
__device__ __forceinline__ float dpp_addf(float x) {
  int t = __builtin_amdgcn_update_dpp(0, __float_as_int(x), CTRL, 0xF, 0xF, false);
  return x + __int_as_float(t);
}
// Type-safe float broadcast from lane 0 (readlane builtin is int-typed; a bare float
// arg would TRUNCATE — that was a past correctness bug).
__device__ __forceinline__ float bcast0_f(float x) {
  return __int_as_float(__builtin_amdgcn_readfirstlane(__float_as_int(x)));
}

// ---- K1: row L2-normalize (4 rows/block) + binning (first 40 blocks) -------
// (cellCnt/ovfCnt are zeroed by a hipMemsetAsync before this launch.)
__global__ __launch_bounds__(256) void prep_bin_kernel(const float* __restrict__ x,
                                                       float* __restrict__ y,
                                                       const int2* __restrict__ pos,
                                                       int* __restrict__ cellCnt,
                                                       int2* __restrict__ bucket,
                                                       int* __restrict__ ovfCnt,
                                                       int2* __restrict__ ovf, int N) {
  const int j = blockIdx.x * 256 + threadIdx.x;
  if (j < N) {
    int2 p = pos[j];
    const int cell = (p.y >> CSH) * GW + (p.x >> CSH);
    const int s = atomicAdd(&cellCnt[cell], 1);
    const int2 e = make_int2(p.x | (p.y << 16), j);   // packed (x,y) + original index
    if (s < BCAP) bucket[cell * BCAP + s] = e;
    else { int o = atomicAdd(ovfCnt, 1); if (o < OVCAP) ovf[o] = e; }  // exactness spill
  }
  const int row = blockIdx.x * 4 + (threadIdx.x >> 6);
  if (row >= N) return;
  const int lane = threadIdx.x & 63;
  float4 v = ((const float4*)(x + (size_t)row * FD))[lane];
  float ss = v.x * v.x + v.y * v.y + v.z * v.z + v.w * v.w;
  // butterfly reduce: 32/16 cross-row via DS shuffle, 8/4/2/1 via DPP (bit-identical at lane 0)
  ss += __shfl_down(ss, 32);
  ss += __shfl_down(ss, 16);
  ss = dpp_addf<0x108>(ss);   // row_shl:8
  ss = dpp_addf<0x104>(ss);
  ss = dpp_addf<0x102>(ss);
  ss = dpp_addf<0x101>(ss);
  ss = bcast0_f(ss);                          // bit-cast broadcast (no int truncation!)
  const float d = fmaxf(sqrtf(ss), 1e-12f);   // F.normalize eps semantics
  float4 o4;
  o4.x = v.x / d; o4.y = v.y / d; o4.z = v.z / d; o4.w = v.w / d;
  ((float4*)(y + (size_t)row * FD))[lane] = o4;
}

// ---- K2: wave-per-query exact spatial top-30 + cosine top-6 (no barriers) --
// Dense cell-major query assignment computed IN-WAVE (prefix over clamped cellCnt
// via DPP scan). Dot phase: 4 candidates/iteration on 16-lane rows — lane (r,p)
// dots candidate selj[4c+r]'s float4 blocks {p,p+16,p+32,p+48}, combines them as
// (d0+d2)+(d1+d3) (== the old butterfly's o=32/o=16 steps) then DPP 8/4/2/1.
// Lane p==0 result is BIT-IDENTICAL to the old 64-lane tree; zero DS-shuffles.
// Occupancy 8 blocks/CU (32 waves = HW max): no software prefetch in the dot —
// the added TLP hides L2 latency; q-fragments loaded AFTER the R-loop to keep
// VGPR <= 64 (8 waves/EU budget).
__global__ __launch_bounds__(256, 8) void graph_kernel(const int2* __restrict__ pos,
                                                       const int* __restrict__ cellCnt,
                                                       const int2* __restrict__ bucket,
                                                       const int* __restrict__ ovfCnt,
                                                       const int2* __restrict__ ovf,
                                                       const float* __restrict__ fn,
                                                       float* __restrict__ outI,
                                                       float* __restrict__ outW, int N) {
  __shared__ unsigned long long surv[4][SCAPW];
  __shared__ int pfx[4][MAXC + 1];
  __shared__ int cbase[4][MAXC];
  __shared__ int hist[4][64];
  __shared__ float sims[4][KS];
  __shared__ int selj[4][KS + 2];   // +2 padding slots for the 4-wide dot groups
  __shared__ int wsel[4][KF];
  __shared__ int kd2[4];

  const int w = threadIdx.x >> 6, lane = threadIdx.x & 63;

  // XCD-aware bijective block swizzle: give each of the 8 XCDs a CONTIGUOUS
  // cell-major chunk so its private 4MB L2 holds that region's fn rows (+halo).
  const int nwg = gridDim.x, orig = blockIdx.x;
  const int qq = nwg >> 3, rr = nwg & 7;
  const int xcd = orig & 7, idx = orig >> 3;
  const int bid = (xcd < rr ? xcd * (qq + 1) : rr * (qq + 1) + (xcd - rr) * qq) + idx;

  const int qi = bid * 4 + w;             // dense query rank (cell-major)
  if (qi >= N) return;                    // wave-uniform; no block barriers anywhere
  const int ovfN = min(*ovfCnt, OVCAP);   // ~always 0; uniform L2 broadcast load

  // ---- locate qi: chunked prefix over min(cellCnt,BCAP), cell = 256c+4l+k ----
  int i;                                   // query point index (wave-uniform)
  {
    const int4* cc4 = (const int4*)cellCnt;
    int cnts[4][4], lexcl[4], cbases[4];
    int runbase = 0;
#pragma unroll
    for (int c = 0; c < 4; ++c) {
      int4 v = cc4[c * 64 + lane];         // coalesced; L2-broadcast across waves
      cnts[c][0] = min(v.x, BCAP); cnts[c][1] = min(v.y, BCAP);
      cnts[c][2] = min(v.z, BCAP); cnts[c][3] = min(v.w, BCAP);
      int s = cnts[c][0] + cnts[c][1] + cnts[c][2] + cnts[c][3];
      int incl = iscan64(s);               // DPP scan (VALU, no DS traffic)
      lexcl[c] = incl - s;
      cbases[c] = runbase;
      runbase += __builtin_amdgcn_readlane(incl, 63);   // chunk total (int: safe)
    }
    const int total = runbase;             // == #bucketed points
    if (qi < total) {
      int fcell = -1, fslot = 0;
#pragma unroll
      for (int c = 0; c < 4; ++c) {
        int p = cbases[c] + lexcl[c];
#pragma unroll
        for (int k = 0; k < 4; ++k) {
          int cn = cnts[c][k];
          if (qi >= p && qi < p + cn) { fcell = (c * 64 + lane) * 4 + k; fslot = qi - p; }
          p += cn;
        }
      }
      const unsigned long long m = __ballot(fcell >= 0);
      const int src = __ffsll((unsigned long long)m) - 1;   // wave-uniform
      fcell = __builtin_amdgcn_readlane(fcell, src);        // int: safe
      fslot = __builtin_amdgcn_readlane(fslot, src);
      i = bucket[fcell * BCAP + fslot].y;
    } else {
      i = ovf[qi - total].y;               // overflow queries (~never)
    }
  }

  unsigned long long* survw = surv[w];
  int* pfxw = pfx[w];
  int* basew = cbase[w];
  int* histw = hist[w];
  float* simsw = sims[w];
  int* seljw = selj[w];
  int* wselw = wsel[w];

  const int2 q = pos[i];
  const int qx = q.x, qy = q.y;
  const int cx = qx >> CSH, cy = qy >> CSH;
  const int p16 = lane & 15;
  const int r4 = lane >> 4;

  int R = 2;
  int sn = 0;
  for (;;) {
    // ---- list the (2R+1)^2 square's cells; chunked DPP prefix-scan ----
    const int W = 2 * R + 1;
    const int ns = min(W * W, MAXC);
    int run = 0;
    for (int cb = 0; cb < ns; cb += 64) {
      const int s = cb + lane;
      int cnt = 0, base = 0;
      if (s < ns) {
        int dy = s / W - R, dx = s % W - R;
        int yy = cy + dy, xx = cx + dx;
        if (yy >= 0 && yy < GW && xx >= 0 && xx < GW) {
          int cid = yy * GW + xx;
          cnt = min(cellCnt[cid], BCAP);   // parallel global loads, L2-hot
          base = cid * BCAP;
        }
      }
      int incl = iscan64(cnt);
      if (s < ns) { pfxw[s] = run + incl - cnt; basew[s] = base; }
      run += __builtin_amdgcn_readlane(incl, 63);
    }
    if (lane == 0) pfxw[ns] = run;
    WFENCE();
    const int M = run;
    const int MM = min(M + ovfN, 64 * KREG);   // clamp guard (same drop semantics as before)

    // ---- build candidate keys into registers: (d2<<16)|j, self -> ~0 ----
    unsigned long long kreg[KREG];
#pragma unroll
    for (int s8 = 0; s8 < KREG; ++s8) {
      kreg[s8] = ~0ull;
      const int m = lane + 64 * s8;
      if (m < MM) {
        int2 e;
        if (m < M) {
          int c = 0;                          // binary search: largest c, pfx[c] <= m
#pragma unroll
          for (int st = 64; st; st >>= 1) { int nc = c + st; if (nc < ns && pfxw[nc] <= m) c = nc; }
          e = bucket[basew[c] + (m - pfxw[c])];
        } else {
          e = ovf[m - M];
        }
        const int j = e.y;
        if (j != i) {
          int x = e.x & 0xffff, y = e.x >> 16;
          int dx = qx - x, dy = qy - y;
          unsigned d2 = (unsigned)(dx * dx + dy * dy);
          kreg[s8] = (((unsigned long long)d2) << 16) | (unsigned)j;
        }
      }
    }

    // ---- 64-bucket d2 histogram (width 64) -> threshold via ballot ----
    histw[lane] = 0;
    WFENCE();
#pragma unroll
    for (int s8 = 0; s8 < KREG; ++s8)
      if (kreg[s8] != ~0ull)
        atomicAdd(&histw[min((int)(kreg[s8] >> 22), 63)], 1);   // key>>22 == d2>>6
    WFENCE();
    int cum = iscan64(histw[lane]);
    const unsigned long long bal = __ballot(cum >= KS);
    unsigned long long Tk;
    if (bal == 0) Tk = 0x7fffffffull << 16;           // all valid keys survive
    else {
      int bb = __ffsll((unsigned long long)bal) - 1;  // first bucket with cum>=KS
      Tk = (bb == 63) ? (0x7fffffffull << 16) : (((unsigned long long)(bb + 1) << 6) << 16);
    }

    // ---- ballot-prefix compact of survivors (no atomics) ----
    int sbase = 0;
#pragma unroll
    for (int s8 = 0; s8 < KREG; ++s8) {
      const bool p = kreg[s8] < Tk;                   // self ~0 never survives
      const unsigned long long mask = __ballot(p);
      if (p) {
        int idx2 = sbase + __popcll(mask & ((1ull << lane) - 1));
        if (idx2 < SCAPW) survw[idx2] = kreg[s8];     // clamp guard, P~1e-40
      }
      sbase += __popcll(mask);
    }
    sn = min(sbase, SCAPW);
    WFENCE();

    // ---- exact stable top-KS by rank-by-count over survivors ----
    for (int p = lane; p < sn; p += 64) {
      const unsigned long long kp = survw[p];
      int r = 0;
      for (int s = 0; s < sn; ++s) r += (survw[s] < kp) ? 1 : 0;  // LDS broadcast reads
      if (r < KS) seljw[r] = (int)(kp & 0xffffu);
      if (r == KS - 1) kd2[w] = (int)(kp >> 16);
    }
    WFENCE();

    // ---- exactness: 30th d2 must strictly beat anything outside the square ----
    bool done = false;
    if (sn >= KS) {
      const int kthd2 = kd2[w];
      int sg = 1 << 15;                 // "infinite" when all sides reach the domain edge
      if (cx - R > 0)      sg = min(sg, qx - ((cx - R) << CSH));
      if (cx + R < GW - 1) sg = min(sg, (((cx + R) << CSH) + 15) - qx);
      if (cy - R > 0)      sg = min(sg, qy - ((cy - R) << CSH));
      if (cy + R < GW - 1) sg = min(sg, (((cy + R) << CSH) + 15) - qy);
      done = kthd2 < (sg + 1) * (sg + 1);
    }
    if (done) break;
    ++R;                                // rare: re-scan the bigger square from scratch
  }

  // pad candidate list to NGRP*4 entries (duplicate last; sims write is guarded)
  if (lane == 0) { seljw[KS] = seljw[KS - 1]; seljw[KS + 1] = seljw[KS - 1]; }
  WFENCE();

  // query fragments for the 16-lane-row dot scheme: lane needs q blocks
  // {p, p+16, p+32, p+48}. Loaded here (not before the R-loop) to cap VGPR at 64.
  const float4* qp = (const float4*)(fn + (size_t)i * FD);
  const float4 qA = qp[p16];
  const float4 qB = qp[p16 + 16];
  const float4 qC = qp[p16 + 32];
  const float4 qD = qp[p16 + 48];

  // ---- cosine sims: 4 candidates/iteration on 16-lane rows, zero DS-shuffles.
  //      Lane (r4,p16) dots candidate selj[4c+r4] blocks {p,p+16,p+32,p+48};
  //      (d0+d2)+(d1+d3) then DPP row_shl 8/4/2/1 == old 64-lane tree at p==0.
  //      No software prefetch: 32-wave occupancy hides the L2 latency. ----
#pragma unroll
  for (int c = 0; c < NGRP; ++c) {
    const float4* rp = (const float4*)(fn + (size_t)seljw[c * 4 + r4] * FD);
    const float4 fA = rp[p16];
    const float4 fB = rp[p16 + 16];
    const float4 fC = rp[p16 + 32];
    const float4 fD = rp[p16 + 48];
    const float d0 = fA.x * qA.x + fA.y * qA.y + fA.z * qA.z + fA.w * qA.w;
    const float d1 = fB.x * qB.x + fB.y * qB.y + fB.z * qB.z + fB.w * qB.w;
    const float d2 = fC.x * qC.x + fC.y * qC.y + fC.z * qC.z + fC.w * qC.w;
    const float d3 = fD.x * qD.x + fD.y * qD.y + fD.z * qD.z + fD.w * qD.w;
    float b = (d0 + d2) + (d1 + d3);   // == butterfly steps o=32, o=16 at lane p
    b = dpp_addf<0x108>(b);   // row_shl:8
    b = dpp_addf<0x104>(b);   // row_shl:4
    b = dpp_addf<0x102>(b);   // row_shl:2
    b = dpp_addf<0x101>(b);   // row_shl:1
    const int cc = c * 4 + r4;
    if (p16 == 0 && cc < KS) simsw[cc] = b;
  }
  WFENCE();

  // ---- stable top-KF (desc value, asc index on ties) ----
  if (lane < KS) {
    const float simv = simsw[lane];
    int r = 0;
    for (int s = 0; s < KS; ++s) {
      const float so = simsw[s];
      if (so > simv || (so == simv && s < lane)) ++r;
    }
    if (r < KF) wselw[r] = lane;
  }
  WFENCE();

  // ---- softmax over the 6 selected; lanes 0-5 write (same math as before) ----
  if (lane < KF) {
    const float m = simsw[wselw[0]];    // rank 0 == max
    float sum = 0.f, my = 0.f;
#pragma unroll
    for (int r = 0; r < KF; ++r) {
      float e = expf(simsw[wselw[r]] - m);
      sum += e;
      if (r == lane) my = e;
    }
    outI[(size_t)i * KF + lane] = (float)seljw[wselw[lane]];
    outW[(size_t)i * KF + lane] = my / sum;
  }
}

extern "C" void kernel_launch(void* const* d_in, const int* in_sizes, int n_in,
                              void* d_out, int out_size, void* d_ws, size_t ws_size,
                              hipStream_t stream) {
  const float* feat = (const float*)d_in[0];   // [N, 256] fp32
  const int2* pos = (const int2*)d_in[1];      // [N, 2] int32
  const int N = in_sizes[1] / 2;

  char* ws = (char*)d_ws;
  float* fn = (float*)ws;                        // N*256 f32 = 10.24 MB
  size_t off = (size_t)N * FD * sizeof(float);
  int* cellCnt = (int*)(ws + off);  off += NCELLS * sizeof(int);
  int* ovfCnt  = (int*)(ws + off);  off += 2 * sizeof(int);            // keep 8B align
  int2* bucket = (int2*)(ws + off); off += (size_t)NCELLS * BCAP * sizeof(int2);
  int2* ovf    = (int2*)(ws + off); off += OVCAP * sizeof(int2);       // ~10.6 MB total

  float* out = (float*)d_out;                    // [N*6] indices (as f32) ++ [N*6] weights

  // zero cellCnt (4096 B) + ovfCnt (8 B, contiguous) via a single async memset
  // (graph-capture-safe stream op; replaces the serialized single-block zero_kernel)
  hipMemsetAsync(cellCnt, 0, NCELLS * sizeof(int) + 2 * sizeof(int), stream);
  prep_bin_kernel<<<(N + 3) / 4, 256, 0, stream>>>(feat, fn, pos, cellCnt, bucket,
                                                   ovfCnt, ovf, N);
  graph_kernel<<<(N + 3) / 4, 256, 0, stream>>>(pos, cellCnt, bucket, ovfCnt, ovf, fn,
                                                out, out + (size_t)N * KF, N);
}

// Round 5
// 96.184 us; speedup vs baseline: 1.0375x; 1.0375x over previous
//
#include <hip/hip_runtime.h>
#include <cstdint>
#include <cstddef>

// Problem constants (fixed by reference setup_inputs: N=10000, D=256, pos in [0,512)^2)
#define FD    256     // feature dim
#define KS    30      // spatial k
#define KF    6       // feature k
#define CSH   4       // cell size 16 px
#define GW    32      // 32x32 cell grid
#define NCELLS (GW*GW)
#define BCAP  40      // bucket capacity/cell (Poisson lambda=9.8; P(>40)~1e-13; overflow->ovf, still exact)
#define OVCAP 128     // global overflow list capacity
#define KREG  8       // candidate key slots per lane (wave covers 512; R=2 square ~245)
#define SCAPW 96      // survivors per wave (~40-60 typical; clamp guard beyond)
#define MAXC  100     // max cells per round (R<=4 square = 81)
#define NGRP  8       // dot phase: 8 groups x 4 candidates (30 real + 2 padded)

// Compiler memory fence at wave-synchronous LDS phase edges (HW LDS is in-order per wave).
#define WFENCE() __threadfence_block()

// ---- DPP cross-lane helpers: VALU-pipe replacements for ds_bpermute shuffles ----
// row_shr:N = lane i gets lane i-N (within 16-lane row); row_shl:N = lane i gets i+N.
// update_dpp(old=0,...) -> invalid/masked lanes contribute 0 to the add.
template <int CTRL, int RM, int BM>
__device__ __forceinline__ int dpp_add_i(int x) {
  return x + __builtin_amdgcn_update_dpp(0, x, CTRL, RM, BM, false);
}
// Canonical 64-lane inclusive scan: 4x row_shr + row_bcast15(rows 1,3) + row_bcast31(rows 2,3).
__device__ __forceinline__ int iscan64(int x) {
  x = dpp_add_i<0x111, 0xF, 0xF>(x);   // row_shr:1
  x = dpp_add_i<0x112, 0xF, 0xF>(x);   // row_shr:2
  x = dpp_add_i<0x114, 0xF, 0xF>(x);   // row_shr:4
  x = dpp_add_i<0x118, 0xF, 0xF>(x);   // row_shr:8
  x = dpp_add_i<0x142, 0xA, 0xF>(x);   // row_bcast:15 -> rows 1,3
  x = dpp_add_i<0x143, 0xC, 0xF>(x);   // row_bcast:31 -> rows 2,3
  return x;
}
// Wave-total of a per-lane int (scan + readlane 63).
__device__ __forceinline__ int wsum64(int x) {
  return __builtin_amdgcn_readlane(iscan64(x), 63);
}
// Butterfly step lane i += lane i+N (in-row, row_shl:N). Bit-identical to __shfl_down
// for every lane that feeds lane 0's reduction tree (steps <=8 only source in-row lanes).
template <int CTRL>
__device__ __forceinline__ float dpp_addf(float x) {
  int t = __builtin_amdgcn_update_dpp(0, __float_as_int(x), CTRL, 0xF, 0xF, false);
  return x + __int_as_float(t);
}
// Type-safe float broadcast from lane 0 (readlane builtin is int-typed; a bare float
// arg would TRUNCATE — that was a past correctness bug).
__device__ __forceinline__ float bcast0_f(float x) {
  return __int_as_float(__builtin_amdgcn_readfirstlane(__float_as_int(x)));
}

// ---- K0: zero bin counters (must precede the binning atomics) --------------
__global__ __launch_bounds__(1024) void zero_kernel(int* __restrict__ cellCnt,
                                                    int* __restrict__ ovfCnt) {
  cellCnt[threadIdx.x] = 0;
  if (threadIdx.x == 0) *ovfCnt = 0;
}

// ---- K1: row L2-normalize (4 rows/block) + binning (first 40 blocks) -------
__global__ __launch_bounds__(256) void prep_bin_kernel(const float* __restrict__ x,
                                                       float* __restrict__ y,
                                                       const int2* __restrict__ pos,
                                                       int* __restrict__ cellCnt,
                                                       int2* __restrict__ bucket,
                                                       int* __restrict__ ovfCnt,
                                                       int2* __restrict__ ovf, int N) {
  const int j = blockIdx.x * 256 + threadIdx.x;
  if (j < N) {
    int2 p = pos[j];
    const int cell = (p.y >> CSH) * GW + (p.x >> CSH);
    const int s = atomicAdd(&cellCnt[cell], 1);
    const int2 e = make_int2(p.x | (p.y << 16), j);   // packed (x,y) + original index
    if (s < BCAP) bucket[cell * BCAP + s] = e;
    else { int o = atomicAdd(ovfCnt, 1); if (o < OVCAP) ovf[o] = e; }  // exactness spill
  }
  const int row = blockIdx.x * 4 + (threadIdx.x >> 6);
  if (row >= N) return;
  const int lane = threadIdx.x & 63;
  float4 v = ((const float4*)(x + (size_t)row * FD))[lane];
  float ss = v.x * v.x + v.y * v.y + v.z * v.z + v.w * v.w;
  // butterfly reduce: 32/16 cross-row via DS shuffle, 8/4/2/1 via DPP (bit-identical at lane 0)
  ss += __shfl_down(ss, 32);
  ss += __shfl_down(ss, 16);
  ss = dpp_addf<0x108>(ss);   // row_shl:8
  ss = dpp_addf<0x104>(ss);
  ss = dpp_addf<0x102>(ss);
  ss = dpp_addf<0x101>(ss);
  ss = bcast0_f(ss);                          // bit-cast broadcast (no int truncation!)
  const float d = fmaxf(sqrtf(ss), 1e-12f);   // F.normalize eps semantics
  float4 o4;
  o4.x = v.x / d; o4.y = v.y / d; o4.z = v.z / d; o4.w = v.w / d;
  ((float4*)(y + (size_t)row * FD))[lane] = o4;
}

// ---- K2: wave-per-query exact spatial top-30 + cosine top-6 (no barriers) --
// Dense cell-major query assignment computed IN-WAVE (prefix over clamped cellCnt
// via DPP scan). Threshold selection: DPP binary search over bucket boundaries
// (provably identical result to the old LDS-atomic histogram + scan, but pure
// VALU — the old histogram degenerated to ~5 hot buckets => ~50-way same-address
// LDS-atomic serialization). Dot phase: 4 candidates/iteration on 16-lane rows,
// bit-identical sum tree, 2-deep prefetch (proven in round 3).
__global__ __launch_bounds__(256, 6) void graph_kernel(const int2* __restrict__ pos,
                                                       const int* __restrict__ cellCnt,
                                                       const int2* __restrict__ bucket,
                                                       const int* __restrict__ ovfCnt,
                                                       const int2* __restrict__ ovf,
                                                       const float* __restrict__ fn,
                                                       float* __restrict__ outI,
                                                       float* __restrict__ outW, int N) {
  __shared__ unsigned long long surv[4][SCAPW];
  __shared__ int pfx[4][MAXC + 1];
  __shared__ int cbase[4][MAXC];
  __shared__ float sims[4][KS];
  __shared__ int selj[4][KS + 2];   // +2 padding slots for the 4-wide dot groups
  __shared__ int wsel[4][KF];
  __shared__ int kd2[4];

  const int w = threadIdx.x >> 6, lane = threadIdx.x & 63;

  // XCD-aware bijective block swizzle: give each of the 8 XCDs a CONTIGUOUS
  // cell-major chunk so its private 4MB L2 holds that region's fn rows (+halo).
  const int nwg = gridDim.x, orig = blockIdx.x;
  const int qq = nwg >> 3, rr = nwg & 7;
  const int xcd = orig & 7, idx = orig >> 3;
  const int bid = (xcd < rr ? xcd * (qq + 1) : rr * (qq + 1) + (xcd - rr) * qq) + idx;

  const int qi = bid * 4 + w;             // dense query rank (cell-major)
  if (qi >= N) return;                    // wave-uniform; no block barriers anywhere
  const int ovfN = min(*ovfCnt, OVCAP);   // ~always 0; uniform L2 broadcast load

  // ---- locate qi: chunked prefix over min(cellCnt,BCAP), cell = 256c+4l+k ----
  int i;                                   // query point index (wave-uniform)
  {
    const int4* cc4 = (const int4*)cellCnt;
    int cnts[4][4], lexcl[4], cbases[4];
    int runbase = 0;
#pragma unroll
    for (int c = 0; c < 4; ++c) {
      int4 v = cc4[c * 64 + lane];         // coalesced; L2-broadcast across waves
      cnts[c][0] = min(v.x, BCAP); cnts[c][1] = min(v.y, BCAP);
      cnts[c][2] = min(v.z, BCAP); cnts[c][3] = min(v.w, BCAP);
      int s = cnts[c][0] + cnts[c][1] + cnts[c][2] + cnts[c][3];
      int incl = iscan64(s);               // DPP scan (VALU, no DS traffic)
      lexcl[c] = incl - s;
      cbases[c] = runbase;
      runbase += __builtin_amdgcn_readlane(incl, 63);   // chunk total (int: safe)
    }
    const int total = runbase;             // == #bucketed points
    if (qi < total) {
      int fcell = -1, fslot = 0;
#pragma unroll
      for (int c = 0; c < 4; ++c) {
        int p = cbases[c] + lexcl[c];
#pragma unroll
        for (int k = 0; k < 4; ++k) {
          int cn = cnts[c][k];
          if (qi >= p && qi < p + cn) { fcell = (c * 64 + lane) * 4 + k; fslot = qi - p; }
          p += cn;
        }
      }
      const unsigned long long m = __ballot(fcell >= 0);
      const int src = __ffsll((unsigned long long)m) - 1;   // wave-uniform
      fcell = __builtin_amdgcn_readlane(fcell, src);        // int: safe
      fslot = __builtin_amdgcn_readlane(fslot, src);
      i = bucket[fcell * BCAP + fslot].y;
    } else {
      i = ovf[qi - total].y;               // overflow queries (~never)
    }
  }

  unsigned long long* survw = surv[w];
  int* pfxw = pfx[w];
  int* basew = cbase[w];
  float* simsw = sims[w];
  int* seljw = selj[w];
  int* wselw = wsel[w];

  const int2 q = pos[i];
  const int qx = q.x, qy = q.y;
  const int cx = qx >> CSH, cy = qy >> CSH;

  // query fragments for the 16-lane-row dot scheme: lane needs q blocks
  // {p, p+16, p+32, p+48} (p = lane&15). Loaded early to hide L2 latency.
  const int p16 = lane & 15;
  const int r4 = lane >> 4;
  const float4* qp = (const float4*)(fn + (size_t)i * FD);
  const float4 qA = qp[p16];
  const float4 qB = qp[p16 + 16];
  const float4 qC = qp[p16 + 32];
  const float4 qD = qp[p16 + 48];

  int R = 2;
  int sn = 0;
  for (;;) {
    // ---- list the (2R+1)^2 square's cells; chunked DPP prefix-scan ----
    const int W = 2 * R + 1;
    const int ns = min(W * W, MAXC);
    int run = 0;
    for (int cb = 0; cb < ns; cb += 64) {
      const int s = cb + lane;
      int cnt = 0, base = 0;
      if (s < ns) {
        int dy = s / W - R, dx = s % W - R;
        int yy = cy + dy, xx = cx + dx;
        if (yy >= 0 && yy < GW && xx >= 0 && xx < GW) {
          int cid = yy * GW + xx;
          cnt = min(cellCnt[cid], BCAP);   // parallel global loads, L2-hot
          base = cid * BCAP;
        }
      }
      int incl = iscan64(cnt);
      if (s < ns) { pfxw[s] = run + incl - cnt; basew[s] = base; }
      run += __builtin_amdgcn_readlane(incl, 63);
    }
    if (lane == 0) pfxw[ns] = run;
    WFENCE();
    const int M = run;
    const int MM = min(M + ovfN, 64 * KREG);   // clamp guard (same drop semantics as before)

    // ---- build candidate keys into registers: (d2<<16)|j, self -> ~0 ----
    unsigned long long kreg[KREG];
    int bkt[KREG];                       // clamped d2 bucket; 64 = invalid sentinel
#pragma unroll
    for (int s8 = 0; s8 < KREG; ++s8) {
      kreg[s8] = ~0ull;
      bkt[s8] = 64;
      const int m = lane + 64 * s8;
      if (m < MM) {
        int2 e;
        if (m < M) {
          int c = 0;                          // binary search: largest c, pfx[c] <= m
#pragma unroll
          for (int st = 64; st; st >>= 1) { int nc = c + st; if (nc < ns && pfxw[nc] <= m) c = nc; }
          e = bucket[basew[c] + (m - pfxw[c])];
        } else {
          e = ovf[m - M];
        }
        const int j = e.y;
        if (j != i) {
          int x = e.x & 0xffff, y = e.x >> 16;
          int dx = qx - x, dy = qy - y;
          unsigned d2 = (unsigned)(dx * dx + dy * dy);
          kreg[s8] = (((unsigned long long)d2) << 16) | (unsigned)j;
          bkt[s8] = min((int)(d2 >> 6), 63);
        }
      }
    }

    // ---- threshold bucket via DPP binary search (== old histogram result) ----
    // Find largest bb in [0,63] with count(bkt < bb) < KS  (count monotone ->
    // greedy bit-build). bb is then the minimal bucket with cum >= KS, or 63
    // when none/clamped — both of which map to Tk = INF exactly as before.
    int bb = 0;
#pragma unroll
    for (int st = 32; st; st >>= 1) {
      const int t = bb + st;
      int c = 0;
#pragma unroll
      for (int s8 = 0; s8 < KREG; ++s8) c += (bkt[s8] < t) ? 1 : 0;
      if (wsum64(c) < KS) bb = t;
    }
    const unsigned long long Tk = (bb >= 63) ? (0x7fffffffull << 16)
                                             : (((unsigned long long)(bb + 1) << 6) << 16);

    // ---- ballot-prefix compact of survivors (no atomics) ----
    int sbase = 0;
#pragma unroll
    for (int s8 = 0; s8 < KREG; ++s8) {
      const bool p = kreg[s8] < Tk;                   // self ~0 never survives
      const unsigned long long mask = __ballot(p);
      if (p) {
        int idx2 = sbase + __popcll(mask & ((1ull << lane) - 1));
        if (idx2 < SCAPW) survw[idx2] = kreg[s8];     // clamp guard, P~1e-40
      }
      sbase += __popcll(mask);
    }
    sn = min(sbase, SCAPW);
    WFENCE();

    // ---- exact stable top-KS by rank-by-count over survivors ----
    for (int p = lane; p < sn; p += 64) {
      const unsigned long long kp = survw[p];
      int r = 0;
      for (int s = 0; s < sn; ++s) r += (survw[s] < kp) ? 1 : 0;  // LDS broadcast reads
      if (r < KS) seljw[r] = (int)(kp & 0xffffu);
      if (r == KS - 1) kd2[w] = (int)(kp >> 16);
    }
    WFENCE();

    // ---- exactness: 30th d2 must strictly beat anything outside the square ----
    bool done = false;
    if (sn >= KS) {
      const int kthd2 = kd2[w];
      int sg = 1 << 15;                 // "infinite" when all sides reach the domain edge
      if (cx - R > 0)      sg = min(sg, qx - ((cx - R) << CSH));
      if (cx + R < GW - 1) sg = min(sg, (((cx + R) << CSH) + 15) - qx);
      if (cy - R > 0)      sg = min(sg, qy - ((cy - R) << CSH));
      if (cy + R < GW - 1) sg = min(sg, (((cy + R) << CSH) + 15) - qy);
      done = kthd2 < (sg + 1) * (sg + 1);
    }
    if (done) break;
    ++R;                                // rare: re-scan the bigger square from scratch
  }

  // pad candidate list to NGRP*4 entries (duplicate last; sims write is guarded)
  if (lane == 0) { seljw[KS] = seljw[KS - 1]; seljw[KS + 1] = seljw[KS - 1]; }
  WFENCE();

  // ---- cosine sims: 4 candidates/iteration on 16-lane rows, zero DS-shuffles.
  //      Lane (r4,p16) dots candidate selj[4c+r4] blocks {p,p+16,p+32,p+48};
  //      (d0+d2)+(d1+d3) then DPP row_shl 8/4/2/1 == old 64-lane tree at p==0.
  //      2-deep prefetch, fully unrolled (static buffer indices, no scratch). ----
  float4 fb0A, fb0B, fb0C, fb0D;   // buffer 0
  float4 fb1A, fb1B, fb1C, fb1D;   // buffer 1
  {
    const float4* rp = (const float4*)(fn + (size_t)seljw[r4] * FD);
    fb0A = rp[p16]; fb0B = rp[p16 + 16]; fb0C = rp[p16 + 32]; fb0D = rp[p16 + 48];
  }
#pragma unroll
  for (int c = 0; c < NGRP; ++c) {
    const bool even = (c & 1) == 0;
    if (c + 1 < NGRP) {
      const float4* rp = (const float4*)(fn + (size_t)seljw[(c + 1) * 4 + r4] * FD);
      if (even) { fb1A = rp[p16]; fb1B = rp[p16 + 16]; fb1C = rp[p16 + 32]; fb1D = rp[p16 + 48]; }
      else      { fb0A = rp[p16]; fb0B = rp[p16 + 16]; fb0C = rp[p16 + 32]; fb0D = rp[p16 + 48]; }
    }
    const float4 fA = even ? fb0A : fb1A;
    const float4 fB = even ? fb0B : fb1B;
    const float4 fC = even ? fb0C : fb1C;
    const float4 fD = even ? fb0D : fb1D;
    const float d0 = fA.x * qA.x + fA.y * qA.y + fA.z * qA.z + fA.w * qA.w;
    const float d1 = fB.x * qB.x + fB.y * qB.y + fB.z * qB.z + fB.w * qB.w;
    const float d2 = fC.x * qC.x + fC.y * qC.y + fC.z * qC.z + fC.w * qC.w;
    const float d3 = fD.x * qD.x + fD.y * qD.y + fD.z * qD.z + fD.w * qD.w;
    float b = (d0 + d2) + (d1 + d3);   // == butterfly steps o=32, o=16 at lane p
    b = dpp_addf<0x108>(b);   // row_shl:8
    b = dpp_addf<0x104>(b);   // row_shl:4
    b = dpp_addf<0x102>(b);   // row_shl:2
    b = dpp_addf<0x101>(b);   // row_shl:1
    const int cc = c * 4 + r4;
    if (p16 == 0 && cc < KS) simsw[cc] = b;
  }
  WFENCE();

  // ---- stable top-KF (desc value, asc index on ties) ----
  if (lane < KS) {
    const float simv = simsw[lane];
    int r = 0;
    for (int s = 0; s < KS; ++s) {
      const float so = simsw[s];
      if (so > simv || (so == simv && s < lane)) ++r;
    }
    if (r < KF) wselw[r] = lane;
  }
  WFENCE();

  // ---- softmax over the 6 selected; lanes 0-5 write (same math as before) ----
  if (lane < KF) {
    const float m = simsw[wselw[0]];    // rank 0 == max
    float sum = 0.f, my = 0.f;
#pragma unroll
    for (int r = 0; r < KF; ++r) {
      float e = expf(simsw[wselw[r]] - m);
      sum += e;
      if (r == lane) my = e;
    }
    outI[(size_t)i * KF + lane] = (float)seljw[wselw[lane]];
    outW[(size_t)i * KF + lane] = my / sum;
  }
}

extern "C" void kernel_launch(void* const* d_in, const int* in_sizes, int n_in,
                              void* d_out, int out_size, void* d_ws, size_t ws_size,
                              hipStream_t stream) {
  const float* feat = (const float*)d_in[0];   // [N, 256] fp32
  const int2* pos = (const int2*)d_in[1];      // [N, 2] int32
  const int N = in_sizes[1] / 2;

  char* ws = (char*)d_ws;
  float* fn = (float*)ws;                        // N*256 f32 = 10.24 MB
  size_t off = (size_t)N * FD * sizeof(float);
  int* cellCnt = (int*)(ws + off);  off += NCELLS * sizeof(int);
  int* ovfCnt  = (int*)(ws + off);  off += 2 * sizeof(int);            // keep 8B align
  int2* bucket = (int2*)(ws + off); off += (size_t)NCELLS * BCAP * sizeof(int2);
  int2* ovf    = (int2*)(ws + off); off += OVCAP * sizeof(int2);       // ~10.6 MB total

  float* out = (float*)d_out;                    // [N*6] indices (as f32) ++ [N*6] weights

  zero_kernel<<<1, 1024, 0, stream>>>(cellCnt, ovfCnt);
  prep_bin_kernel<<<(N + 3) / 4, 256, 0, stream>>>(feat, fn, pos, cellCnt, bucket,
                                                   ovfCnt, ovf, N);
  graph_kernel<<<(N + 3) / 4, 256, 0, stream>>>(pos, cellCnt, bucket, ovfCnt, ovf, fn,
                                                out, out + (size_t)N * KF, N);
}

// Round 6
// 96.003 us; speedup vs baseline: 1.0394x; 1.0019x over previous
//
#include <hip/hip_runtime.h>
#include <cstdint>
#include <cstddef>

// Problem constants (fixed by reference setup_inputs: N=10000, D=256, pos in [0,512)^2)
#define FD    256     // feature dim
#define KS    30      // spatial k
#define KF    6       // feature k
#define CSH   4       // cell size 16 px
#define GW    32      // 32x32 cell grid
#define NCELLS (GW*GW)
#define BCAP  40      // bucket capacity/cell (Poisson lambda=9.8; P(>40)~1e-13; overflow->ovf, still exact)
#define OVCAP 128     // global overflow list capacity
#define KREG  8       // candidate key slots per lane (wave covers 512; R=2 square ~245)
#define SCAPW 96      // survivors per wave (~40-60 typical; clamp guard beyond)
#define MAXC  100     // max cells per round (R<=4 square = 81)
#define NGRP  8       // dot phase: 8 groups x 4 candidates (30 real + 2 padded)

// Compiler memory fence at wave-synchronous LDS phase edges (HW LDS is in-order per wave).
#define WFENCE() __threadfence_block()

// ---- DPP cross-lane helpers: VALU-pipe replacements for ds_bpermute shuffles ----
// row_shr:N = lane i gets lane i-N (within 16-lane row); row_shl:N = lane i gets i+N.
// update_dpp(old=0,...) -> invalid/masked lanes contribute 0 to the add.
template <int CTRL, int RM, int BM>
__device__ __forceinline__ int dpp_add_i(int x) {
  return x + __builtin_amdgcn_update_dpp(0, x, CTRL, RM, BM, false);
}
// Canonical 64-lane inclusive scan: 4x row_shr + row_bcast15(rows 1,3) + row_bcast31(rows 2,3).
__device__ __forceinline__ int iscan64(int x) {
  x = dpp_add_i<0x111, 0xF, 0xF>(x);   // row_shr:1
  x = dpp_add_i<0x112, 0xF, 0xF>(x);   // row_shr:2
  x = dpp_add_i<0x114, 0xF, 0xF>(x);   // row_shr:4
  x = dpp_add_i<0x118, 0xF, 0xF>(x);   // row_shr:8
  x = dpp_add_i<0x142, 0xA, 0xF>(x);   // row_bcast:15 -> rows 1,3
  x = dpp_add_i<0x143, 0xC, 0xF>(x);   // row_bcast:31 -> rows 2,3
  return x;
}
// Butterfly step lane i += lane i+N (in-row, row_shl:N). Bit-identical to __shfl_down
// for every lane that feeds lane 0's reduction tree (steps <=8 only source in-row lanes).
template <int CTRL>
__device__ __forceinline__ float dpp_addf(float x) {
  int t = __builtin_amdgcn_update_dpp(0, __float_as_int(x), CTRL, 0xF, 0xF, false);
  return x + __int_as_float(t);
}
// Type-safe float broadcast from lane 0 (readlane builtin is int-typed; a bare float
// arg would TRUNCATE — that was a past correctness bug).
__device__ __forceinline__ float bcast0_f(float x) {
  return __int_as_float(__builtin_amdgcn_readfirstlane(__float_as_int(x)));
}

// ---- K0: zero bin counters (must precede the binning atomics) --------------
__global__ __launch_bounds__(1024) void zero_kernel(int* __restrict__ cellCnt,
                                                    int* __restrict__ ovfCnt) {
  cellCnt[threadIdx.x] = 0;
  if (threadIdx.x == 0) *ovfCnt = 0;
}

// ---- K1: row L2-normalize (4 rows/block) + binning (first 40 blocks) -------
__global__ __launch_bounds__(256) void prep_bin_kernel(const float* __restrict__ x,
                                                       float* __restrict__ y,
                                                       const int2* __restrict__ pos,
                                                       int* __restrict__ cellCnt,
                                                       int2* __restrict__ bucket,
                                                       int* __restrict__ ovfCnt,
                                                       int2* __restrict__ ovf, int N) {
  const int j = blockIdx.x * 256 + threadIdx.x;
  if (j < N) {
    int2 p = pos[j];
    const int cell = (p.y >> CSH) * GW + (p.x >> CSH);
    const int s = atomicAdd(&cellCnt[cell], 1);
    const int2 e = make_int2(p.x | (p.y << 16), j);   // packed (x,y) + original index
    if (s < BCAP) bucket[cell * BCAP + s] = e;
    else { int o = atomicAdd(ovfCnt, 1); if (o < OVCAP) ovf[o] = e; }  // exactness spill
  }
  const int row = blockIdx.x * 4 + (threadIdx.x >> 6);
  if (row >= N) return;
  const int lane = threadIdx.x & 63;
  float4 v = ((const float4*)(x + (size_t)row * FD))[lane];
  float ss = v.x * v.x + v.y * v.y + v.z * v.z + v.w * v.w;
  // butterfly reduce: 32/16 cross-row via DS shuffle, 8/4/2/1 via DPP (bit-identical at lane 0)
  ss += __shfl_down(ss, 32);
  ss += __shfl_down(ss, 16);
  ss = dpp_addf<0x108>(ss);   // row_shl:8
  ss = dpp_addf<0x104>(ss);
  ss = dpp_addf<0x102>(ss);
  ss = dpp_addf<0x101>(ss);
  ss = bcast0_f(ss);                          // bit-cast broadcast (no int truncation!)
  const float d = fmaxf(sqrtf(ss), 1e-12f);   // F.normalize eps semantics
  float4 o4;
  o4.x = v.x / d; o4.y = v.y / d; o4.z = v.z / d; o4.w = v.w / d;
  ((float4*)(y + (size_t)row * FD))[lane] = o4;
}

// ---- K2: wave-per-query exact spatial top-30 + cosine top-6 (no barriers) --
// Dense cell-major query assignment computed IN-WAVE (prefix over clamped cellCnt
// via DPP scan). Dot phase: 4 candidates/iteration on 16-lane rows — lane (r,p)
// dots candidate selj[4c+r]'s float4 blocks {p,p+16,p+32,p+48}, combines them as
// (d0+d2)+(d1+d3) (== the old butterfly's o=32/o=16 steps) then DPP 8/4/2/1.
// Lane p==0 result is BIT-IDENTICAL to the old 64-lane tree; zero DS-shuffles.
// Prefetch is DISTANCE-2 at the same 2-buffer register cost: iteration c reads
// buffer c%2 then immediately re-issues it with group c+2's loads (WAR on the
// same regs — reads precede the overwriting load), doubling latency cover.
__global__ __launch_bounds__(256, 6) void graph_kernel(const int2* __restrict__ pos,
                                                       const int* __restrict__ cellCnt,
                                                       const int2* __restrict__ bucket,
                                                       const int* __restrict__ ovfCnt,
                                                       const int2* __restrict__ ovf,
                                                       const float* __restrict__ fn,
                                                       float* __restrict__ outI,
                                                       float* __restrict__ outW, int N) {
  __shared__ unsigned long long surv[4][SCAPW];
  __shared__ int pfx[4][MAXC + 1];
  __shared__ int cbase[4][MAXC];
  __shared__ int hist[4][64];
  __shared__ float sims[4][KS];
  __shared__ int selj[4][KS + 2];   // +2 padding slots for the 4-wide dot groups
  __shared__ int wsel[4][KF];
  __shared__ int kd2[4];

  const int w = threadIdx.x >> 6, lane = threadIdx.x & 63;

  // XCD-aware bijective block swizzle: give each of the 8 XCDs a CONTIGUOUS
  // cell-major chunk so its private 4MB L2 holds that region's fn rows (+halo).
  const int nwg = gridDim.x, orig = blockIdx.x;
  const int qq = nwg >> 3, rr = nwg & 7;
  const int xcd = orig & 7, idx = orig >> 3;
  const int bid = (xcd < rr ? xcd * (qq + 1) : rr * (qq + 1) + (xcd - rr) * qq) + idx;

  const int qi = bid * 4 + w;             // dense query rank (cell-major)
  if (qi >= N) return;                    // wave-uniform; no block barriers anywhere
  const int ovfN = min(*ovfCnt, OVCAP);   // ~always 0; uniform L2 broadcast load

  // ---- locate qi: chunked prefix over min(cellCnt,BCAP), cell = 256c+4l+k ----
  int i;                                   // query point index (wave-uniform)
  {
    const int4* cc4 = (const int4*)cellCnt;
    int cnts[4][4], lexcl[4], cbases[4];
    int runbase = 0;
#pragma unroll
    for (int c = 0; c < 4; ++c) {
      int4 v = cc4[c * 64 + lane];         // coalesced; L2-broadcast across waves
      cnts[c][0] = min(v.x, BCAP); cnts[c][1] = min(v.y, BCAP);
      cnts[c][2] = min(v.z, BCAP); cnts[c][3] = min(v.w, BCAP);
      int s = cnts[c][0] + cnts[c][1] + cnts[c][2] + cnts[c][3];
      int incl = iscan64(s);               // DPP scan (VALU, no DS traffic)
      lexcl[c] = incl - s;
      cbases[c] = runbase;
      runbase += __builtin_amdgcn_readlane(incl, 63);   // chunk total (int: safe)
    }
    const int total = runbase;             // == #bucketed points
    if (qi < total) {
      int fcell = -1, fslot = 0;
#pragma unroll
      for (int c = 0; c < 4; ++c) {
        int p = cbases[c] + lexcl[c];
#pragma unroll
        for (int k = 0; k < 4; ++k) {
          int cn = cnts[c][k];
          if (qi >= p && qi < p + cn) { fcell = (c * 64 + lane) * 4 + k; fslot = qi - p; }
          p += cn;
        }
      }
      const unsigned long long m = __ballot(fcell >= 0);
      const int src = __ffsll((unsigned long long)m) - 1;   // wave-uniform
      fcell = __builtin_amdgcn_readlane(fcell, src);        // int: safe
      fslot = __builtin_amdgcn_readlane(fslot, src);
      i = bucket[fcell * BCAP + fslot].y;
    } else {
      i = ovf[qi - total].y;               // overflow queries (~never)
    }
  }

  unsigned long long* survw = surv[w];
  int* pfxw = pfx[w];
  int* basew = cbase[w];
  int* histw = hist[w];
  float* simsw = sims[w];
  int* seljw = selj[w];
  int* wselw = wsel[w];

  const int2 q = pos[i];
  const int qx = q.x, qy = q.y;
  const int cx = qx >> CSH, cy = qy >> CSH;

  // query fragments for the 16-lane-row dot scheme: lane needs q blocks
  // {p, p+16, p+32, p+48} (p = lane&15). Loaded early to hide L2 latency.
  const int p16 = lane & 15;
  const int r4 = lane >> 4;
  const float4* qp = (const float4*)(fn + (size_t)i * FD);
  const float4 qA = qp[p16];
  const float4 qB = qp[p16 + 16];
  const float4 qC = qp[p16 + 32];
  const float4 qD = qp[p16 + 48];

  int R = 2;
  int sn = 0;
  for (;;) {
    // ---- list the (2R+1)^2 square's cells; chunked DPP prefix-scan ----
    const int W = 2 * R + 1;
    const int ns = min(W * W, MAXC);
    int run = 0;
    for (int cb = 0; cb < ns; cb += 64) {
      const int s = cb + lane;
      int cnt = 0, base = 0;
      if (s < ns) {
        int dy = s / W - R, dx = s % W - R;
        int yy = cy + dy, xx = cx + dx;
        if (yy >= 0 && yy < GW && xx >= 0 && xx < GW) {
          int cid = yy * GW + xx;
          cnt = min(cellCnt[cid], BCAP);   // parallel global loads, L2-hot
          base = cid * BCAP;
        }
      }
      int incl = iscan64(cnt);
      if (s < ns) { pfxw[s] = run + incl - cnt; basew[s] = base; }
      run += __builtin_amdgcn_readlane(incl, 63);
    }
    if (lane == 0) pfxw[ns] = run;
    WFENCE();
    const int M = run;
    const int MM = min(M + ovfN, 64 * KREG);   // clamp guard (same drop semantics as before)

    // ---- build candidate keys into registers: (d2<<16)|j, self -> ~0 ----
    unsigned long long kreg[KREG];
#pragma unroll
    for (int s8 = 0; s8 < KREG; ++s8) {
      kreg[s8] = ~0ull;
      const int m = lane + 64 * s8;
      if (m < MM) {
        int2 e;
        if (m < M) {
          int c = 0;                          // binary search: largest c, pfx[c] <= m
#pragma unroll
          for (int st = 64; st; st >>= 1) { int nc = c + st; if (nc < ns && pfxw[nc] <= m) c = nc; }
          e = bucket[basew[c] + (m - pfxw[c])];
        } else {
          e = ovf[m - M];
        }
        const int j = e.y;
        if (j != i) {
          int x = e.x & 0xffff, y = e.x >> 16;
          int dx = qx - x, dy = qy - y;
          unsigned d2 = (unsigned)(dx * dx + dy * dy);
          kreg[s8] = (((unsigned long long)d2) << 16) | (unsigned)j;
        }
      }
    }

    // ---- 64-bucket d2 histogram (width 64) -> threshold via ballot ----
    histw[lane] = 0;
    WFENCE();
#pragma unroll
    for (int s8 = 0; s8 < KREG; ++s8)
      if (kreg[s8] != ~0ull)
        atomicAdd(&histw[min((int)(kreg[s8] >> 22), 63)], 1);   // key>>22 == d2>>6
    WFENCE();
    int cum = iscan64(histw[lane]);
    const unsigned long long bal = __ballot(cum >= KS);
    unsigned long long Tk;
    if (bal == 0) Tk = 0x7fffffffull << 16;           // all valid keys survive
    else {
      int bb = __ffsll((unsigned long long)bal) - 1;  // first bucket with cum>=KS
      Tk = (bb == 63) ? (0x7fffffffull << 16) : (((unsigned long long)(bb + 1) << 6) << 16);
    }

    // ---- ballot-prefix compact of survivors (no atomics) ----
    int sbase = 0;
#pragma unroll
    for (int s8 = 0; s8 < KREG; ++s8) {
      const bool p = kreg[s8] < Tk;                   // self ~0 never survives
      const unsigned long long mask = __ballot(p);
      if (p) {
        int idx2 = sbase + __popcll(mask & ((1ull << lane) - 1));
        if (idx2 < SCAPW) survw[idx2] = kreg[s8];     // clamp guard, P~1e-40
      }
      sbase += __popcll(mask);
    }
    sn = min(sbase, SCAPW);
    WFENCE();

    // ---- exact stable top-KS by rank-by-count over survivors ----
    for (int p = lane; p < sn; p += 64) {
      const unsigned long long kp = survw[p];
      int r = 0;
      for (int s = 0; s < sn; ++s) r += (survw[s] < kp) ? 1 : 0;  // LDS broadcast reads
      if (r < KS) seljw[r] = (int)(kp & 0xffffu);
      if (r == KS - 1) kd2[w] = (int)(kp >> 16);
    }
    WFENCE();

    // ---- exactness: 30th d2 must strictly beat anything outside the square ----
    bool done = false;
    if (sn >= KS) {
      const int kthd2 = kd2[w];
      int sg = 1 << 15;                 // "infinite" when all sides reach the domain edge
      if (cx - R > 0)      sg = min(sg, qx - ((cx - R) << CSH));
      if (cx + R < GW - 1) sg = min(sg, (((cx + R) << CSH) + 15) - qx);
      if (cy - R > 0)      sg = min(sg, qy - ((cy - R) << CSH));
      if (cy + R < GW - 1) sg = min(sg, (((cy + R) << CSH) + 15) - qy);
      done = kthd2 < (sg + 1) * (sg + 1);
    }
    if (done) break;
    ++R;                                // rare: re-scan the bigger square from scratch
  }

  // pad candidate list to NGRP*4 entries (duplicate last; sims write is guarded)
  if (lane == 0) { seljw[KS] = seljw[KS - 1]; seljw[KS + 1] = seljw[KS - 1]; }
  WFENCE();

  // ---- cosine sims: 4 candidates/iteration on 16-lane rows, zero DS-shuffles.
  //      Lane (r4,p16) dots candidate selj[4c+r4] blocks {p,p+16,p+32,p+48};
  //      (d0+d2)+(d1+d3) then DPP row_shl 8/4/2/1 == old 64-lane tree at p==0.
  //      DISTANCE-2 prefetch on 2 buffers: consume buffer c%2, then re-issue it
  //      with group c+2 (reads precede the WAR overwrite; ~2 iterations of L2
  //      latency in flight vs distance-1 before). Fully unrolled, static regs. ----
  float4 fb0A, fb0B, fb0C, fb0D;   // buffer 0
  float4 fb1A, fb1B, fb1C, fb1D;   // buffer 1
  {
    const float4* rp = (const float4*)(fn + (size_t)seljw[r4] * FD);
    fb0A = rp[p16]; fb0B = rp[p16 + 16]; fb0C = rp[p16 + 32]; fb0D = rp[p16 + 48];
  }
  {
    const float4* rp = (const float4*)(fn + (size_t)seljw[4 + r4] * FD);
    fb1A = rp[p16]; fb1B = rp[p16 + 16]; fb1C = rp[p16 + 32]; fb1D = rp[p16 + 48];
  }
#pragma unroll
  for (int c = 0; c < NGRP; ++c) {
    const bool even = (c & 1) == 0;
    // consume current buffer into SSA temps (renames, not copies after regalloc)
    const float4 fA = even ? fb0A : fb1A;
    const float4 fB = even ? fb0B : fb1B;
    const float4 fC = even ? fb0C : fb1C;
    const float4 fD = even ? fb0D : fb1D;
    // re-issue the just-consumed buffer with group c+2 (distance-2 prefetch)
    if (c + 2 < NGRP) {
      const float4* rp = (const float4*)(fn + (size_t)seljw[(c + 2) * 4 + r4] * FD);
      if (even) { fb0A = rp[p16]; fb0B = rp[p16 + 16]; fb0C = rp[p16 + 32]; fb0D = rp[p16 + 48]; }
      else      { fb1A = rp[p16]; fb1B = rp[p16 + 16]; fb1C = rp[p16 + 32]; fb1D = rp[p16 + 48]; }
    }
    const float d0 = fA.x * qA.x + fA.y * qA.y + fA.z * qA.z + fA.w * qA.w;
    const float d1 = fB.x * qB.x + fB.y * qB.y + fB.z * qB.z + fB.w * qB.w;
    const float d2 = fC.x * qC.x + fC.y * qC.y + fC.z * qC.z + fC.w * qC.w;
    const float d3 = fD.x * qD.x + fD.y * qD.y + fD.z * qD.z + fD.w * qD.w;
    float b = (d0 + d2) + (d1 + d3);   // == butterfly steps o=32, o=16 at lane p
    b = dpp_addf<0x108>(b);   // row_shl:8
    b = dpp_addf<0x104>(b);   // row_shl:4
    b = dpp_addf<0x102>(b);   // row_shl:2
    b = dpp_addf<0x101>(b);   // row_shl:1
    const int cc = c * 4 + r4;
    if (p16 == 0 && cc < KS) simsw[cc] = b;
  }
  WFENCE();

  // ---- stable top-KF (desc value, asc index on ties) ----
  if (lane < KS) {
    const float simv = simsw[lane];
    int r = 0;
    for (int s = 0; s < KS; ++s) {
      const float so = simsw[s];
      if (so > simv || (so == simv && s < lane)) ++r;
    }
    if (r < KF) wselw[r] = lane;
  }
  WFENCE();

  // ---- softmax over the 6 selected; lanes 0-5 write (same math as before) ----
  if (lane < KF) {
    const float m = simsw[wselw[0]];    // rank 0 == max
    float sum = 0.f, my = 0.f;
#pragma unroll
    for (int r = 0; r < KF; ++r) {
      float e = expf(simsw[wselw[r]] - m);
      sum += e;
      if (r == lane) my = e;
    }
    outI[(size_t)i * KF + lane] = (float)seljw[wselw[lane]];
    outW[(size_t)i * KF + lane] = my / sum;
  }
}

extern "C" void kernel_launch(void* const* d_in, const int* in_sizes, int n_in,
                              void* d_out, int out_size, void* d_ws, size_t ws_size,
                              hipStream_t stream) {
  const float* feat = (const float*)d_in[0];   // [N, 256] fp32
  const int2* pos = (const int2*)d_in[1];      // [N, 2] int32
  const int N = in_sizes[1] / 2;

  char* ws = (char*)d_ws;
  float* fn = (float*)ws;                        // N*256 f32 = 10.24 MB
  size_t off = (size_t)N * FD * sizeof(float);
  int* cellCnt = (int*)(ws + off);  off += NCELLS * sizeof(int);
  int* ovfCnt  = (int*)(ws + off);  off += 2 * sizeof(int);            // keep 8B align
  int2* bucket = (int2*)(ws + off); off += (size_t)NCELLS * BCAP * sizeof(int2);
  int2* ovf    = (int2*)(ws + off); off += OVCAP * sizeof(int2);       // ~10.6 MB total

  float* out = (float*)d_out;                    // [N*6] indices (as f32) ++ [N*6] weights

  zero_kernel<<<1, 1024, 0, stream>>>(cellCnt, ovfCnt);
  prep_bin_kernel<<<(N + 3) / 4, 256, 0, stream>>>(feat, fn, pos, cellCnt, bucket,
                                                   ovfCnt, ovf, N);
  graph_kernel<<<(N + 3) / 4, 256, 0, stream>>>(pos, cellCnt, bucket, ovfCnt, ovf, fn,
                                                out, out + (size_t)N * KF, N);
}

// Round 7
// 95.174 us; speedup vs baseline: 1.0485x; 1.0087x over previous
//
#include <hip/hip_runtime.h>
#include <cstdint>
#include <cstddef>

// Problem constants (fixed by reference setup_inputs: N=10000, D=256, pos in [0,512)^2)
#define FD    256     // feature dim
#define KS    30      // spatial k
#define KF    6       // feature k
#define CSH   4       // cell size 16 px
#define GW    32      // 32x32 cell grid
#define NCELLS (GW*GW)
#define BCAP  40      // bucket capacity/cell (Poisson lambda=9.8; P(>40)~1e-13; overflow->ovf, still exact)
#define OVCAP 128     // global overflow list capacity
#define KREG  6       // candidate key slots per lane (384 >= M~Poisson(245)+9sigma; P(clamp)~1e-19)
#define SCAPW 96      // survivors per wave (~40-60 typical; clamp guard beyond)
#define MAXC  100     // max cells per round (R<=4 square = 81)
#define NGRP  8       // dot phase: 8 groups x 4 candidates (30 real + 2 padded)

// Compiler memory fence at wave-synchronous LDS phase edges (HW LDS is in-order per wave).
#define WFENCE() __threadfence_block()

// ---- DPP cross-lane helpers: VALU-pipe replacements for ds_bpermute shuffles ----
template <int CTRL, int RM, int BM>
__device__ __forceinline__ int dpp_add_i(int x) {
  return x + __builtin_amdgcn_update_dpp(0, x, CTRL, RM, BM, false);
}
// Canonical 64-lane inclusive scan: 4x row_shr + row_bcast15(rows 1,3) + row_bcast31(rows 2,3).
__device__ __forceinline__ int iscan64(int x) {
  x = dpp_add_i<0x111, 0xF, 0xF>(x);   // row_shr:1
  x = dpp_add_i<0x112, 0xF, 0xF>(x);   // row_shr:2
  x = dpp_add_i<0x114, 0xF, 0xF>(x);   // row_shr:4
  x = dpp_add_i<0x118, 0xF, 0xF>(x);   // row_shr:8
  x = dpp_add_i<0x142, 0xA, 0xF>(x);   // row_bcast:15 -> rows 1,3
  x = dpp_add_i<0x143, 0xC, 0xF>(x);   // row_bcast:31 -> rows 2,3
  return x;
}
// Butterfly step lane i += lane i+N (in-row, row_shl:N). Bit-identical to __shfl_down
// for every lane that feeds lane 0's reduction tree (steps <=8 only source in-row lanes).
template <int CTRL>
__device__ __forceinline__ float dpp_addf(float x) {
  int t = __builtin_amdgcn_update_dpp(0, __float_as_int(x), CTRL, 0xF, 0xF, false);
  return x + __int_as_float(t);
}
// Type-safe float broadcast from lane 0 (readlane builtin is int-typed; a bare float
// arg would TRUNCATE — that was a past correctness bug).
__device__ __forceinline__ float bcast0_f(float x) {
  return __int_as_float(__builtin_amdgcn_readfirstlane(__float_as_int(x)));
}

// ---- K0: zero bin counters (must precede the binning atomics) --------------
__global__ __launch_bounds__(1024) void zero_kernel(int* __restrict__ cellCnt,
                                                    int* __restrict__ ovfCnt) {
  cellCnt[threadIdx.x] = 0;
  if (threadIdx.x == 0) *ovfCnt = 0;
}

// ---- K1: row L2-normalize (4 rows/block) + binning (first 40 blocks) -------
__global__ __launch_bounds__(256) void prep_bin_kernel(const float* __restrict__ x,
                                                       float* __restrict__ y,
                                                       const int2* __restrict__ pos,
                                                       int* __restrict__ cellCnt,
                                                       int2* __restrict__ bucket,
                                                       int* __restrict__ ovfCnt,
                                                       int2* __restrict__ ovf, int N) {
  const int j = blockIdx.x * 256 + threadIdx.x;
  if (j < N) {
    int2 p = pos[j];
    const int cell = (p.y >> CSH) * GW + (p.x >> CSH);
    const int s = atomicAdd(&cellCnt[cell], 1);
    const int2 e = make_int2(p.x | (p.y << 16), j);   // packed (x,y) + original index
    if (s < BCAP) bucket[cell * BCAP + s] = e;
    else { int o = atomicAdd(ovfCnt, 1); if (o < OVCAP) ovf[o] = e; }  // exactness spill
  }
  const int row = blockIdx.x * 4 + (threadIdx.x >> 6);
  if (row >= N) return;
  const int lane = threadIdx.x & 63;
  float4 v = ((const float4*)(x + (size_t)row * FD))[lane];
  float ss = v.x * v.x + v.y * v.y + v.z * v.z + v.w * v.w;
  // butterfly reduce: 32/16 cross-row via DS shuffle, 8/4/2/1 via DPP (bit-identical at lane 0)
  ss += __shfl_down(ss, 32);
  ss += __shfl_down(ss, 16);
  ss = dpp_addf<0x108>(ss);   // row_shl:8
  ss = dpp_addf<0x104>(ss);
  ss = dpp_addf<0x102>(ss);
  ss = dpp_addf<0x101>(ss);
  ss = bcast0_f(ss);                          // bit-cast broadcast (no int truncation!)
  const float d = fmaxf(sqrtf(ss), 1e-12f);   // F.normalize eps semantics
  float4 o4;
  o4.x = v.x / d; o4.y = v.y / d; o4.z = v.z / d; o4.w = v.w / d;
  ((float4*)(y + (size_t)row * FD))[lane] = o4;
}

// ---- K2: wave-per-query exact spatial top-30 + cosine top-6 (no barriers) --
// Dense cell-major query assignment computed IN-WAVE (prefix over clamped cellCnt
// via DPP scan). Candidate addressing: during the cell scan each lane (one cell)
// writes addrm[excl+k] = base+k for its k<cnt — the candidate build then does ONE
// independent LDS read per slot instead of a 7-step DEPENDENT binary search over
// pfx[] (removes ~840cy serial LDS chain + ~170 VALU inst per R-iteration).
// Dot phase: 4 candidates/iteration on 16-lane rows, bit-identical sum tree,
// distance-1 2-buffer prefetch (best-measured, round 3).
__global__ __launch_bounds__(256, 6) void graph_kernel(const int2* __restrict__ pos,
                                                       const int* __restrict__ cellCnt,
                                                       const int2* __restrict__ bucket,
                                                       const int* __restrict__ ovfCnt,
                                                       const int2* __restrict__ ovf,
                                                       const float* __restrict__ fn,
                                                       float* __restrict__ outI,
                                                       float* __restrict__ outW, int N) {
  __shared__ unsigned long long surv[4][SCAPW];
  __shared__ int addrm[4][64 * KREG];   // flat candidate m -> bucket address
  __shared__ int hist[4][64];
  __shared__ float sims[4][KS];
  __shared__ int selj[4][KS + 2];   // +2 padding slots for the 4-wide dot groups
  __shared__ int wsel[4][KF];
  __shared__ int kd2[4];

  const int w = threadIdx.x >> 6, lane = threadIdx.x & 63;

  // XCD-aware bijective block swizzle: give each of the 8 XCDs a CONTIGUOUS
  // cell-major chunk so its private 4MB L2 holds that region's fn rows (+halo).
  const int nwg = gridDim.x, orig = blockIdx.x;
  const int qq = nwg >> 3, rr = nwg & 7;
  const int xcd = orig & 7, idx = orig >> 3;
  const int bid = (xcd < rr ? xcd * (qq + 1) : rr * (qq + 1) + (xcd - rr) * qq) + idx;

  const int qi = bid * 4 + w;             // dense query rank (cell-major)
  if (qi >= N) return;                    // wave-uniform; no block barriers anywhere
  const int ovfN = min(*ovfCnt, OVCAP);   // ~always 0; uniform L2 broadcast load

  // ---- locate qi: chunked prefix over min(cellCnt,BCAP), cell = 256c+4l+k ----
  int i;                                   // query point index (wave-uniform)
  {
    const int4* cc4 = (const int4*)cellCnt;
    int cnts[4][4], lexcl[4], cbases[4];
    int runbase = 0;
#pragma unroll
    for (int c = 0; c < 4; ++c) {
      int4 v = cc4[c * 64 + lane];         // coalesced; L2-broadcast across waves
      cnts[c][0] = min(v.x, BCAP); cnts[c][1] = min(v.y, BCAP);
      cnts[c][2] = min(v.z, BCAP); cnts[c][3] = min(v.w, BCAP);
      int s = cnts[c][0] + cnts[c][1] + cnts[c][2] + cnts[c][3];
      int incl = iscan64(s);               // DPP scan (VALU, no DS traffic)
      lexcl[c] = incl - s;
      cbases[c] = runbase;
      runbase += __builtin_amdgcn_readlane(incl, 63);   // chunk total (int: safe)
    }
    const int total = runbase;             // == #bucketed points
    if (qi < total) {
      int fcell = -1, fslot = 0;
#pragma unroll
      for (int c = 0; c < 4; ++c) {
        int p = cbases[c] + lexcl[c];
#pragma unroll
        for (int k = 0; k < 4; ++k) {
          int cn = cnts[c][k];
          if (qi >= p && qi < p + cn) { fcell = (c * 64 + lane) * 4 + k; fslot = qi - p; }
          p += cn;
        }
      }
      const unsigned long long m = __ballot(fcell >= 0);
      const int src = __ffsll((unsigned long long)m) - 1;   // wave-uniform
      fcell = __builtin_amdgcn_readlane(fcell, src);        // int: safe
      fslot = __builtin_amdgcn_readlane(fslot, src);
      i = bucket[fcell * BCAP + fslot].y;
    } else {
      i = ovf[qi - total].y;               // overflow queries (~never)
    }
  }

  unsigned long long* survw = surv[w];
  int* addrw = addrm[w];
  int* histw = hist[w];
  float* simsw = sims[w];
  int* seljw = selj[w];
  int* wselw = wsel[w];

  const int2 q = pos[i];
  const int qx = q.x, qy = q.y;
  const int cx = qx >> CSH, cy = qy >> CSH;

  // query fragments for the 16-lane-row dot scheme: lane needs q blocks
  // {p, p+16, p+32, p+48} (p = lane&15). Loaded early to hide L2 latency.
  const int p16 = lane & 15;
  const int r4 = lane >> 4;
  const float4* qp = (const float4*)(fn + (size_t)i * FD);
  const float4 qA = qp[p16];
  const float4 qB = qp[p16 + 16];
  const float4 qC = qp[p16 + 32];
  const float4 qD = qp[p16 + 48];

  int R = 2;
  int sn = 0;
  for (;;) {
    // ---- list the (2R+1)^2 square's cells; DPP prefix-scan + addr-map build ----
    const int W = 2 * R + 1;
    const int ns = min(W * W, MAXC);
    int run = 0;
    for (int cb = 0; cb < ns; cb += 64) {
      const int s = cb + lane;
      int cnt = 0, base = 0;
      if (s < ns) {
        int dy = s / W - R, dx = s % W - R;
        int yy = cy + dy, xx = cx + dx;
        if (yy >= 0 && yy < GW && xx >= 0 && xx < GW) {
          int cid = yy * GW + xx;
          cnt = min(cellCnt[cid], BCAP);   // parallel global loads, L2-hot
          base = cid * BCAP;
        }
      }
      const int incl = iscan64(cnt);
      const int excl = run + incl - cnt;   // flat start of this lane's cell
      // ragged scatter: candidate m in [excl, excl+cnt) lives at bucket[base+k].
      // Wave executes max(cnt) iterations (~20 typical); replaces per-slot binary search.
      for (int k = 0; k < cnt; ++k) {
        const int t = excl + k;
        if (t < 64 * KREG) addrw[t] = base + k;   // clamp guard (P~1e-19), same drop semantics
      }
      run += __builtin_amdgcn_readlane(incl, 63);
    }
    WFENCE();
    const int M = run;
    const int MM = min(M + ovfN, 64 * KREG);   // clamp guard (same drop semantics as before)

    // ---- build candidate keys into registers: (d2<<16)|j, self -> ~0 ----
    unsigned long long kreg[KREG];
#pragma unroll
    for (int s8 = 0; s8 < KREG; ++s8) {
      kreg[s8] = ~0ull;
      const int m = lane + 64 * s8;
      if (m < MM) {
        int2 e;
        if (m < M) {
          e = bucket[addrw[m]];             // one independent LDS read + one L2 load
        } else {
          e = ovf[m - M];
        }
        const int j = e.y;
        if (j != i) {
          int x = e.x & 0xffff, y = e.x >> 16;
          int dx = qx - x, dy = qy - y;
          unsigned d2 = (unsigned)(dx * dx + dy * dy);
          kreg[s8] = (((unsigned long long)d2) << 16) | (unsigned)j;
        }
      }
    }

    // ---- 64-bucket d2 histogram (width 64) -> threshold via ballot ----
    histw[lane] = 0;
    WFENCE();
#pragma unroll
    for (int s8 = 0; s8 < KREG; ++s8)
      if (kreg[s8] != ~0ull)
        atomicAdd(&histw[min((int)(kreg[s8] >> 22), 63)], 1);   // key>>22 == d2>>6
    WFENCE();
    int cum = iscan64(histw[lane]);
    const unsigned long long bal = __ballot(cum >= KS);
    unsigned long long Tk;
    if (bal == 0) Tk = 0x7fffffffull << 16;           // all valid keys survive
    else {
      int bb = __ffsll((unsigned long long)bal) - 1;  // first bucket with cum>=KS
      Tk = (bb == 63) ? (0x7fffffffull << 16) : (((unsigned long long)(bb + 1) << 6) << 16);
    }

    // ---- ballot-prefix compact of survivors (no atomics) ----
    int sbase = 0;
#pragma unroll
    for (int s8 = 0; s8 < KREG; ++s8) {
      const bool p = kreg[s8] < Tk;                   // self ~0 never survives
      const unsigned long long mask = __ballot(p);
      if (p) {
        int idx2 = sbase + __popcll(mask & ((1ull << lane) - 1));
        if (idx2 < SCAPW) survw[idx2] = kreg[s8];     // clamp guard, P~1e-40
      }
      sbase += __popcll(mask);
    }
    sn = min(sbase, SCAPW);
    WFENCE();

    // ---- exact stable top-KS by rank-by-count over survivors ----
    for (int p = lane; p < sn; p += 64) {
      const unsigned long long kp = survw[p];
      int r = 0;
      for (int s = 0; s < sn; ++s) r += (survw[s] < kp) ? 1 : 0;  // LDS broadcast reads
      if (r < KS) seljw[r] = (int)(kp & 0xffffu);
      if (r == KS - 1) kd2[w] = (int)(kp >> 16);
    }
    WFENCE();

    // ---- exactness: 30th d2 must strictly beat anything outside the square ----
    bool done = false;
    if (sn >= KS) {
      const int kthd2 = kd2[w];
      int sg = 1 << 15;                 // "infinite" when all sides reach the domain edge
      if (cx - R > 0)      sg = min(sg, qx - ((cx - R) << CSH));
      if (cx + R < GW - 1) sg = min(sg, (((cx + R) << CSH) + 15) - qx);
      if (cy - R > 0)      sg = min(sg, qy - ((cy - R) << CSH));
      if (cy + R < GW - 1) sg = min(sg, (((cy + R) << CSH) + 15) - qy);
      done = kthd2 < (sg + 1) * (sg + 1);
    }
    if (done) break;
    ++R;                                // rare: re-scan the bigger square from scratch
  }

  // pad candidate list to NGRP*4 entries (duplicate last; sims write is guarded)
  if (lane == 0) { seljw[KS] = seljw[KS - 1]; seljw[KS + 1] = seljw[KS - 1]; }
  WFENCE();

  // ---- cosine sims: 4 candidates/iteration on 16-lane rows, zero DS-shuffles.
  //      Lane (r4,p16) dots candidate selj[4c+r4] blocks {p,p+16,p+32,p+48};
  //      (d0+d2)+(d1+d3) then DPP row_shl 8/4/2/1 == old 64-lane tree at p==0.
  //      Distance-1 2-buffer prefetch (round-3 proven config). ----
  float4 fb0A, fb0B, fb0C, fb0D;   // buffer 0
  float4 fb1A, fb1B, fb1C, fb1D;   // buffer 1
  {
    const float4* rp = (const float4*)(fn + (size_t)seljw[r4] * FD);
    fb0A = rp[p16]; fb0B = rp[p16 + 16]; fb0C = rp[p16 + 32]; fb0D = rp[p16 + 48];
  }
#pragma unroll
  for (int c = 0; c < NGRP; ++c) {
    const bool even = (c & 1) == 0;
    if (c + 1 < NGRP) {
      const float4* rp = (const float4*)(fn + (size_t)seljw[(c + 1) * 4 + r4] * FD);
      if (even) { fb1A = rp[p16]; fb1B = rp[p16 + 16]; fb1C = rp[p16 + 32]; fb1D = rp[p16 + 48]; }
      else      { fb0A = rp[p16]; fb0B = rp[p16 + 16]; fb0C = rp[p16 + 32]; fb0D = rp[p16 + 48]; }
    }
    const float4 fA = even ? fb0A : fb1A;
    const float4 fB = even ? fb0B : fb1B;
    const float4 fC = even ? fb0C : fb1C;
    const float4 fD = even ? fb0D : fb1D;
    const float d0 = fA.x * qA.x + fA.y * qA.y + fA.z * qA.z + fA.w * qA.w;
    const float d1 = fB.x * qB.x + fB.y * qB.y + fB.z * qB.z + fB.w * qB.w;
    const float d2 = fC.x * qC.x + fC.y * qC.y + fC.z * qC.z + fC.w * qC.w;
    const float d3 = fD.x * qD.x + fD.y * qD.y + fD.z * qD.z + fD.w * qD.w;
    float b = (d0 + d2) + (d1 + d3);   // == butterfly steps o=32, o=16 at lane p
    b = dpp_addf<0x108>(b);   // row_shl:8
    b = dpp_addf<0x104>(b);   // row_shl:4
    b = dpp_addf<0x102>(b);   // row_shl:2
    b = dpp_addf<0x101>(b);   // row_shl:1
    const int cc = c * 4 + r4;
    if (p16 == 0 && cc < KS) simsw[cc] = b;
  }
  WFENCE();

  // ---- stable top-KF (desc value, asc index on ties) ----
  if (lane < KS) {
    const float simv = simsw[lane];
    int r = 0;
    for (int s = 0; s < KS; ++s) {
      const float so = simsw[s];
      if (so > simv || (so == simv && s < lane)) ++r;
    }
    if (r < KF) wselw[r] = lane;
  }
  WFENCE();

  // ---- softmax over the 6 selected; lanes 0-5 write (same math as before) ----
  if (lane < KF) {
    const float m = simsw[wselw[0]];    // rank 0 == max
    float sum = 0.f, my = 0.f;
#pragma unroll
    for (int r = 0; r < KF; ++r) {
      float e = expf(simsw[wselw[r]] - m);
      sum += e;
      if (r == lane) my = e;
    }
    outI[(size_t)i * KF + lane] = (float)seljw[wselw[lane]];
    outW[(size_t)i * KF + lane] = my / sum;
  }
}

extern "C" void kernel_launch(void* const* d_in, const int* in_sizes, int n_in,
                              void* d_out, int out_size, void* d_ws, size_t ws_size,
                              hipStream_t stream) {
  const float* feat = (const float*)d_in[0];   // [N, 256] fp32
  const int2* pos = (const int2*)d_in[1];      // [N, 2] int32
  const int N = in_sizes[1] / 2;

  char* ws = (char*)d_ws;
  float* fn = (float*)ws;                        // N*256 f32 = 10.24 MB
  size_t off = (size_t)N * FD * sizeof(float);
  int* cellCnt = (int*)(ws + off);  off += NCELLS * sizeof(int);
  int* ovfCnt  = (int*)(ws + off);  off += 2 * sizeof(int);            // keep 8B align
  int2* bucket = (int2*)(ws + off); off += (size_t)NCELLS * BCAP * sizeof(int2);
  int2* ovf    = (int2*)(ws + off); off += OVCAP * sizeof(int2);       // ~10.6 MB total

  float* out = (float*)d_out;                    // [N*6] indices (as f32) ++ [N*6] weights

  zero_kernel<<<1, 1024, 0, stream>>>(cellCnt, ovfCnt);
  prep_bin_kernel<<<(N + 3) / 4, 256, 0, stream>>>(feat, fn, pos, cellCnt, bucket,
                                                   ovfCnt, ovf, N);
  graph_kernel<<<(N + 3) / 4, 256, 0, stream>>>(pos, cellCnt, bucket, ovfCnt, ovf, fn,
                                                out, out + (size_t)N * KF, N);
}